// Round 4
// baseline (111.682 us; speedup 1.0000x reference)
//
#include <hip/hip_runtime.h>
#include <stdint.h>

typedef _Float16 half8 __attribute__((ext_vector_type(8)));
typedef float f32x16 __attribute__((ext_vector_type(16)));

#define NPTS   4096
#define BATCH  16
#define BLOCK  256
#define HOTH   2048               // others per block (one 32 KB LDS stage)
#define NBLK   1024               // dir(2) x b(16) x otherhalf(2) x selftile(16)
#define RBLK   128

// workspace layout (bytes)
#define PART_OFF 0                                  // [2][2][16][4096] float = 1 MiB
#define BSUM_OFF (2 * 2 * BATCH * NPTS * 4)         // [128] float
#define CNT_OFF  (BSUM_OFF + RBLK * 4)              // int ticket counter

// dist(s,o) = |s|^2 + (s.g + q), g = -2o, q = |o|^2, f16 hi/lo split.
// Record R = [ghx,ghy,ghz,glx,gly,glz,qh,ql]; both K-groups read the SAME
// record, the A-fragment differs per group (exact R0 math, absmax 0):
//   grp0: A=[shx,shy,shz,0,0,0,1,0]        -> sh.gh + qh
//   grp1: A=[slx,sly,slz,shx,shy,shz,0,1]  -> sl.gh + sh.gl + ql
// |s|^2 is added per row in the reduce kernel (constant shift commutes w/ min).
__global__ __launch_bounds__(BLOCK, 4) void chamfer_main(
    const float* __restrict__ p1, const float* __restrict__ p2,
    uint8_t* __restrict__ ws)
{
    __shared__ half8 REC[HOTH];    // 32 KB -> 4 blocks/CU, 4 waves/SIMD
    __shared__ float ROWS[256];

    const int tid  = threadIdx.x;
    const int lane = tid & 63;
    const int n    = lane & 31;    // A row (self) / B col (other)
    const int grp  = lane >> 5;    // K-group
    const int wv   = tid >> 6;     // 0..3
    const int blk  = blockIdx.x;
    const int tile = blk & 15;     // fastest: 16 blocks share one other-chunk (L2)
    const int oh   = (blk >> 4) & 1;
    const int b    = (blk >> 5) & 15;
    const int dir  = blk >> 9;

    if (blk == 0 && tid == 0) *(int*)(ws + CNT_OFF) = 0;  // ticket for reduce

    const float* selfp  = (dir ? p2 : p1) + (size_t)b * NPTS * 3;
    const float* otherp = (dir ? p1 : p2) + (size_t)b * NPTS * 3 + (size_t)oh * HOTH * 3;

    {   // Stage 8 others/thread. REC[k*256+tid]: 16 B lane stride -> no bank
        // conflicts (vs tid*8+k = 128 B stride = 32-way). Order is min-invariant.
        const float4* src = (const float4*)otherp;
        float4 v0 = src[tid*6+0], v1 = src[tid*6+1], v2 = src[tid*6+2];
        float4 v3 = src[tid*6+3], v4 = src[tid*6+4], v5 = src[tid*6+5];
        float ox[8] = {v0.x, v0.w, v1.z, v2.y, v3.x, v3.w, v4.z, v5.y};
        float oy[8] = {v0.y, v1.x, v1.w, v2.z, v3.y, v4.x, v4.w, v5.z};
        float oz[8] = {v0.z, v1.y, v2.x, v2.w, v3.z, v4.y, v5.x, v5.w};
#pragma unroll
        for (int k = 0; k < 8; ++k) {
            float gx = -2.f * ox[k], gy = -2.f * oy[k], gz = -2.f * oz[k];
            float q  = fmaf(ox[k], ox[k], fmaf(oy[k], oy[k], oz[k] * oz[k]));
            _Float16 ghx = (_Float16)gx, ghy = (_Float16)gy, ghz = (_Float16)gz;
            half8 r;
            r[0] = ghx; r[1] = ghy; r[2] = ghz;
            r[3] = (_Float16)(gx - (float)ghx);
            r[4] = (_Float16)(gy - (float)ghy);
            r[5] = (_Float16)(gz - (float)ghz);
            _Float16 qh = (_Float16)q;
            r[6] = qh;
            r[7] = (_Float16)(q - (float)qh);
            REC[k * 256 + tid] = r;
        }
    }

    // ---- Two A fragments: selves s0 = base+n, s1 = base+32+n ----
    half8 a0, a1;
    {
        const int i0 = (tile * 256 + wv * 64 + n) * 3, i1 = i0 + 96;
        float x0 = selfp[i0], y0 = selfp[i0 + 1], z0 = selfp[i0 + 2];
        float x1 = selfp[i1], y1 = selfp[i1 + 1], z1 = selfp[i1 + 2];
        _Float16 hx0 = (_Float16)x0, hy0 = (_Float16)y0, hz0 = (_Float16)z0;
        _Float16 lx0 = (_Float16)(x0 - (float)hx0);
        _Float16 ly0 = (_Float16)(y0 - (float)hy0);
        _Float16 lz0 = (_Float16)(z0 - (float)hz0);
        _Float16 hx1 = (_Float16)x1, hy1 = (_Float16)y1, hz1 = (_Float16)z1;
        _Float16 lx1 = (_Float16)(x1 - (float)hx1);
        _Float16 ly1 = (_Float16)(y1 - (float)hy1);
        _Float16 lz1 = (_Float16)(z1 - (float)hz1);
        const _Float16 c0 = (_Float16)0.f, c1 = (_Float16)1.f;
        if (grp == 0) {
            a0[0]=hx0; a0[1]=hy0; a0[2]=hz0; a0[3]=c0; a0[4]=c0; a0[5]=c0; a0[6]=c1; a0[7]=c0;
            a1[0]=hx1; a1[1]=hy1; a1[2]=hz1; a1[3]=c0; a1[4]=c0; a1[5]=c0; a1[6]=c1; a1[7]=c0;
        } else {
            a0[0]=lx0; a0[1]=ly0; a0[2]=lz0; a0[3]=hx0; a0[4]=hy0; a0[5]=hz0; a0[6]=c0; a0[7]=c1;
            a1[0]=lx1; a1[1]=ly1; a1[2]=lz1; a1[3]=hx1; a1[4]=hy1; a1[5]=hz1; a1[6]=c0; a1[7]=c1;
        }
    }

    f32x16 m0, m1, zc;
#pragma unroll
    for (int r = 0; r < 16; ++r) { m0[r] = 3.4e38f; m1[r] = 3.4e38f; zc[r] = 0.f; }

    __syncthreads();

    // 32 g-rounds: 2 ds_read_b128 feed 4 MFMAs (2 selftiles x 2 B-frags)
    const half8* rp = REC + n;
#pragma unroll 4
    for (int g = 0; g < 32; ++g) {
        half8 b0 = rp[g * 64];
        half8 b1 = rp[g * 64 + 32];
        f32x16 o00 = __builtin_amdgcn_mfma_f32_32x32x16_f16(a0, b0, zc, 0, 0, 0);
        f32x16 o01 = __builtin_amdgcn_mfma_f32_32x32x16_f16(a0, b1, zc, 0, 0, 0);
#pragma unroll
        for (int r = 0; r < 16; ++r)
            m0[r] = fminf(fminf(o00[r], o01[r]), m0[r]);   // v_min3_f32
        f32x16 o10 = __builtin_amdgcn_mfma_f32_32x32x16_f16(a1, b0, zc, 0, 0, 0);
        f32x16 o11 = __builtin_amdgcn_mfma_f32_32x32x16_f16(a1, b1, zc, 0, 0, 0);
#pragma unroll
        for (int r = 0; r < 16; ++r)
            m1[r] = fminf(fminf(o10[r], o11[r]), m1[r]);
    }

    // ---- epilogue: min over 32 columns, then per-self partial-min store ----
#pragma unroll
    for (int mask = 1; mask <= 16; mask <<= 1)
#pragma unroll
        for (int r = 0; r < 16; ++r) {
            m0[r] = fminf(m0[r], __shfl_xor((float)m0[r], mask));
            m1[r] = fminf(m1[r], __shfl_xor((float)m1[r], mask));
        }

    // lanes n==0 (one per half) hold this half's 16 rows of each tile
    if (n == 0) {
#pragma unroll
        for (int r = 0; r < 16; ++r) {
            const int row = (r & 3) + 8 * (r >> 2) + 4 * grp;  // C/D row map
            ROWS[wv * 64 + row]      = m0[r];
            ROWS[wv * 64 + 32 + row] = m1[r];
        }
    }
    __syncthreads();

    float* part = (float*)(ws + PART_OFF);
    part[(size_t)oh * (2 * BATCH * NPTS)              // FIX: oh stride = 131072
         + ((size_t)dir * BATCH + b) * NPTS + tile * 256 + tid] = ROWS[tid];
}

// ---------------- reduce: min the two halves, add |s|^2, deterministic sum --
__global__ __launch_bounds__(256) void chamfer_reduce(
    const float* __restrict__ p1, const float* __restrict__ p2,
    uint8_t* __restrict__ ws, float* __restrict__ out)
{
    const float* part = (const float*)(ws + PART_OFF);
    float* bsum = (float*)(ws + BSUM_OFF);
    int*   cnt  = (int*)(ws + CNT_OFF);

    const int t0 = blockIdx.x * 256 + threadIdx.x;   // 0..32767
    float s = 0.f;
#pragma unroll
    for (int i = 0; i < 4; ++i) {
        const int gs  = t0 + i * 32768;              // (dir,b,self) flat
        const int dir = gs >> 16;
        const int rem = gs & 65535;                  // b*4096 + self
        const float* pp = (dir ? p2 : p1) + (size_t)rem * 3;
        const float x = pp[0], y = pp[1], z = pp[2];
        const float ssq = fmaf(x, x, fmaf(y, y, z * z));
        s += fminf(part[gs], part[2 * BATCH * NPTS + gs]) + ssq;
    }
#pragma unroll
    for (int off = 32; off; off >>= 1) s += __shfl_down(s, off, 64);
    __shared__ float ws4[4];
    if ((threadIdx.x & 63) == 0) ws4[threadIdx.x >> 6] = s;
    __syncthreads();
    if (threadIdx.x == 0) {
        bsum[blockIdx.x] = ws4[0] + ws4[1] + ws4[2] + ws4[3];
        __threadfence();
        const int old = atomicAdd(cnt, 1);
        if (old == RBLK - 1) {                       // last block: ordered sum
            __threadfence();
            const volatile float* vb = (const volatile float*)bsum;
            float tot = 0.f;
            for (int i = 0; i < RBLK; ++i) tot += vb[i];
            out[0] = tot * (1.0f / BATCH);
        }
    }
}

extern "C" void kernel_launch(void* const* d_in, const int* in_sizes, int n_in,
                              void* d_out, int out_size, void* d_ws, size_t ws_size,
                              hipStream_t stream) {
    const float* p1 = (const float*)d_in[0];
    const float* p2 = (const float*)d_in[1];
    uint8_t* ws = (uint8_t*)d_ws;
    chamfer_main<<<dim3(NBLK), dim3(BLOCK), 0, stream>>>(p1, p2, ws);
    chamfer_reduce<<<dim3(RBLK), dim3(256), 0, stream>>>(p1, p2, ws, (float*)d_out);
}

// Round 5
// 84.257 us; speedup vs baseline: 1.3255x; 1.3255x over previous
//
#include <hip/hip_runtime.h>
#include <stdint.h>

typedef _Float16 half8 __attribute__((ext_vector_type(8)));
typedef float f32x16 __attribute__((ext_vector_type(16)));

#define NPTS   4096
#define BATCH  16
#define BLOCK  256
#define HOTH   2048               // others per block (one 32 KB LDS stage)
#define NBLK   1024               // tile(16) x oh(2) x b(16) x dir(2)
#define RBLK   128

// workspace layout (bytes)
#define PART_OFF 0                                  // [2(oh)][2(dir)][16][4096] float = 1 MiB
#define BSUM_OFF (2 * 2 * BATCH * NPTS * 4)         // [128] float
#define CNT_OFF  (BSUM_OFF + RBLK * 4)              // int ticket counter

// dist(s,o) = |s|^2 + (s.g + q), g = -2o, q = |o|^2, f16 hi/lo split.
// Record R = [ghx,ghy,ghz,glx,gly,glz,qh,ql]; both K-groups read the SAME
// record, the A-fragment differs per group (exact R0 math, absmax 0):
//   grp0: A=[shx,shy,shz,0,0,0,1,0]        -> sh.gh + qh
//   grp1: A=[slx,sly,slz,shx,shy,shz,0,1]  -> sl.gh + sh.gl + ql
// |s|^2 is added per self in the reduce kernel (constant shift commutes w/ min).
__global__ __launch_bounds__(BLOCK, 4) void chamfer_main(
    const float* __restrict__ p1, const float* __restrict__ p2,
    uint8_t* __restrict__ ws)
{
    __shared__ half8 REC[HOTH];    // 32 KB -> 4 blocks/CU, 4 waves/SIMD
    __shared__ float ROWS[256];

    const int tid  = threadIdx.x;
    const int lane = tid & 63;
    const int n    = lane & 31;    // A row (self) / B col (other)
    const int grp  = lane >> 5;    // K-group
    const int wv   = tid >> 6;     // 0..3
    const int blk  = blockIdx.x;
    const int tile = blk & 15;     // fastest: 16 blocks share one other-chunk (L2)
    const int oh   = (blk >> 4) & 1;
    const int b    = (blk >> 5) & 15;
    const int dir  = blk >> 9;

    if (blk == 0 && tid == 0) *(int*)(ws + CNT_OFF) = 0;  // ticket for reduce

    const float* selfp  = (dir ? p2 : p1) + (size_t)b * NPTS * 3;
    const float* otherp = (dir ? p1 : p2) + (size_t)b * NPTS * 3 + (size_t)oh * HOTH * 3;

    {   // Stage 8 others/thread. REC[k*256+tid]: 16 B lane stride -> no bank
        // conflicts. The k-permutation is min-invariant.
        const float4* src = (const float4*)otherp;
        float4 v0 = src[tid*6+0], v1 = src[tid*6+1], v2 = src[tid*6+2];
        float4 v3 = src[tid*6+3], v4 = src[tid*6+4], v5 = src[tid*6+5];
        float ox[8] = {v0.x, v0.w, v1.z, v2.y, v3.x, v3.w, v4.z, v5.y};
        float oy[8] = {v0.y, v1.x, v1.w, v2.z, v3.y, v4.x, v4.w, v5.z};
        float oz[8] = {v0.z, v1.y, v2.x, v2.w, v3.z, v4.y, v5.x, v5.w};
#pragma unroll
        for (int k = 0; k < 8; ++k) {
            float gx = -2.f * ox[k], gy = -2.f * oy[k], gz = -2.f * oz[k];
            float q  = fmaf(ox[k], ox[k], fmaf(oy[k], oy[k], oz[k] * oz[k]));
            _Float16 ghx = (_Float16)gx, ghy = (_Float16)gy, ghz = (_Float16)gz;
            half8 r;
            r[0] = ghx; r[1] = ghy; r[2] = ghz;
            r[3] = (_Float16)(gx - (float)ghx);
            r[4] = (_Float16)(gy - (float)ghy);
            r[5] = (_Float16)(gz - (float)ghz);
            _Float16 qh = (_Float16)q;
            r[6] = qh;
            r[7] = (_Float16)(q - (float)qh);
            REC[k * 256 + tid] = r;
        }
    }

    // ---- Two A fragments: selves s0 = base+n, s1 = base+32+n ----
    half8 a0, a1;
    {
        const int i0 = (tile * 256 + wv * 64 + n) * 3, i1 = i0 + 96;
        float x0 = selfp[i0], y0 = selfp[i0 + 1], z0 = selfp[i0 + 2];
        float x1 = selfp[i1], y1 = selfp[i1 + 1], z1 = selfp[i1 + 2];
        _Float16 hx0 = (_Float16)x0, hy0 = (_Float16)y0, hz0 = (_Float16)z0;
        _Float16 lx0 = (_Float16)(x0 - (float)hx0);
        _Float16 ly0 = (_Float16)(y0 - (float)hy0);
        _Float16 lz0 = (_Float16)(z0 - (float)hz0);
        _Float16 hx1 = (_Float16)x1, hy1 = (_Float16)y1, hz1 = (_Float16)z1;
        _Float16 lx1 = (_Float16)(x1 - (float)hx1);
        _Float16 ly1 = (_Float16)(y1 - (float)hy1);
        _Float16 lz1 = (_Float16)(z1 - (float)hz1);
        const _Float16 c0 = (_Float16)0.f, c1 = (_Float16)1.f;
        if (grp == 0) {
            a0[0]=hx0; a0[1]=hy0; a0[2]=hz0; a0[3]=c0; a0[4]=c0; a0[5]=c0; a0[6]=c1; a0[7]=c0;
            a1[0]=hx1; a1[1]=hy1; a1[2]=hz1; a1[3]=c0; a1[4]=c0; a1[5]=c0; a1[6]=c1; a1[7]=c0;
        } else {
            a0[0]=lx0; a0[1]=ly0; a0[2]=lz0; a0[3]=hx0; a0[4]=hy0; a0[5]=hz0; a0[6]=c0; a0[7]=c1;
            a1[0]=lx1; a1[1]=ly1; a1[2]=lz1; a1[3]=hx1; a1[4]=hy1; a1[5]=hz1; a1[6]=c0; a1[7]=c1;
        }
    }

    f32x16 m0, m1, zc;
#pragma unroll
    for (int r = 0; r < 16; ++r) { m0[r] = 3.4e38f; m1[r] = 3.4e38f; zc[r] = 0.f; }

    __syncthreads();

    // 32 g-rounds; strict o-register reuse keeps peak live VGPRs ~108 < 128:
    // {o0,o1 from a0 -> fold into m0 (o dead)} then same pair for a1 -> m1.
    const half8* rp = REC + n;
#pragma unroll 2
    for (int g = 0; g < 32; ++g) {
        half8 b0 = rp[g * 64];
        half8 b1 = rp[g * 64 + 32];
        f32x16 o0 = __builtin_amdgcn_mfma_f32_32x32x16_f16(a0, b0, zc, 0, 0, 0);
        f32x16 o1 = __builtin_amdgcn_mfma_f32_32x32x16_f16(a0, b1, zc, 0, 0, 0);
#pragma unroll
        for (int r = 0; r < 16; ++r)
            m0[r] = fminf(fminf(o0[r], o1[r]), m0[r]);   // v_min3_f32
        o0 = __builtin_amdgcn_mfma_f32_32x32x16_f16(a1, b0, zc, 0, 0, 0);
        o1 = __builtin_amdgcn_mfma_f32_32x32x16_f16(a1, b1, zc, 0, 0, 0);
#pragma unroll
        for (int r = 0; r < 16; ++r)
            m1[r] = fminf(fminf(o0[r], o1[r]), m1[r]);
    }

    // ---- epilogue: min over 32 columns, then per-self partial-min store ----
#pragma unroll
    for (int mask = 1; mask <= 16; mask <<= 1)
#pragma unroll
        for (int r = 0; r < 16; ++r) {
            m0[r] = fminf(m0[r], __shfl_xor((float)m0[r], mask));
            m1[r] = fminf(m1[r], __shfl_xor((float)m1[r], mask));
        }

    // lanes n==0 (one per K-group) hold that group's 16 rows of each tile
    if (n == 0) {
#pragma unroll
        for (int r = 0; r < 16; ++r) {
            const int row = (r & 3) + 8 * (r >> 2) + 4 * grp;  // C/D row map
            ROWS[wv * 64 + row]      = m0[r];
            ROWS[wv * 64 + 32 + row] = m1[r];
        }
    }
    __syncthreads();

    float* part = (float*)(ws + PART_OFF);
    part[(size_t)oh * (2 * BATCH * NPTS)
         + ((size_t)dir * BATCH + b) * NPTS + tile * 256 + tid] = ROWS[tid];
}

// ---------------- reduce: min the two halves, add |s|^2, deterministic sum --
__global__ __launch_bounds__(256) void chamfer_reduce(
    const float* __restrict__ p1, const float* __restrict__ p2,
    uint8_t* __restrict__ ws, float* __restrict__ out)
{
    const float* part = (const float*)(ws + PART_OFF);
    float* bsum = (float*)(ws + BSUM_OFF);
    int*   cnt  = (int*)(ws + CNT_OFF);
    __shared__ float ws4[4];
    __shared__ int   isLast;

    const int tid = threadIdx.x;
    const int t0  = blockIdx.x * 256 + tid;          // 0..32767
    float s = 0.f;
#pragma unroll
    for (int i = 0; i < 4; ++i) {
        const int gs  = t0 + i * 32768;              // (dir,b,self) flat
        const int dir = gs >> 16;
        const int rem = gs & 65535;                  // b*4096 + self
        const float* pp = (dir ? p2 : p1) + (size_t)rem * 3;
        const float x = pp[0], y = pp[1], z = pp[2];
        const float ssq = fmaf(x, x, fmaf(y, y, z * z));
        s += fminf(part[gs], part[2 * BATCH * NPTS + gs]) + ssq;
    }
#pragma unroll
    for (int off = 32; off; off >>= 1) s += __shfl_down(s, off, 64);
    if ((tid & 63) == 0) ws4[tid >> 6] = s;
    __syncthreads();
    if (tid == 0) {
        bsum[blockIdx.x] = ws4[0] + ws4[1] + ws4[2] + ws4[3];
        __threadfence();
        isLast = (atomicAdd(cnt, 1) == RBLK - 1);    // release/acquire via cnt
    }
    __syncthreads();
    if (isLast) {                                    // parallel, coherent reads
        float v = (tid < RBLK) ? atomicAdd(&bsum[tid], 0.f) : 0.f;
#pragma unroll
        for (int off = 32; off; off >>= 1) v += __shfl_down(v, off, 64);
        if ((tid & 63) == 0) ws4[tid >> 6] = v;
        __syncthreads();
        if (tid == 0)
            out[0] = (ws4[0] + ws4[1] + ws4[2] + ws4[3]) * (1.0f / BATCH);
    }
}

extern "C" void kernel_launch(void* const* d_in, const int* in_sizes, int n_in,
                              void* d_out, int out_size, void* d_ws, size_t ws_size,
                              hipStream_t stream) {
    const float* p1 = (const float*)d_in[0];
    const float* p2 = (const float*)d_in[1];
    uint8_t* ws = (uint8_t*)d_ws;
    chamfer_main<<<dim3(NBLK), dim3(BLOCK), 0, stream>>>(p1, p2, ws);
    chamfer_reduce<<<dim3(RBLK), dim3(256), 0, stream>>>(p1, p2, ws, (float*)d_out);
}

// Round 6
// 78.245 us; speedup vs baseline: 1.4273x; 1.0768x over previous
//
#include <hip/hip_runtime.h>
#include <stdint.h>

typedef _Float16 half8 __attribute__((ext_vector_type(8)));
typedef float f32x16 __attribute__((ext_vector_type(16)));

#define NPTS   4096
#define BATCH  16
#define BLOCK  256
#define HOTH   2048               // others per LDS stage (32 KB)
#define NCH    2                  // 2 stages cover all 4096 others
#define NBLK   1024               // tile(32 of 128 selves) x b(16) x dir(2) = 4/CU

// dist(s,o) = |s|^2 + (s.g + q), g = -2o, q = |o|^2, f16 hi/lo split.
// Record R = [ghx,ghy,ghz,glx,gly,glz,qh,ql]; both K-groups read the SAME
// record, the A-fragment differs per group (exact R0 math):
//   grp0 (k=0..7):  A=[shx,shy,shz,0,0,0,1,0]        -> sh.gh + qh
//   grp1 (k=8..15): A=[slx,sly,slz,shx,shy,shz,0,1]  -> sl.gh + sh.gl + ql
// One 32x32x16 MFMA therefore yields the full (to ~2^-24) distance tile.
// |s|^2 is added per self in the epilogue (constant shift commutes w/ min).
//
// Register budget (the R4/R5 lesson): unified 128-reg file under
// __launch_bounds__(256,4) splits arch/acc. Accumulators here are EXACTLY
// m(16)+zc(16)+o0(16)+o1(16) = 64; arch side ~30. No spill possible.
__global__ __launch_bounds__(BLOCK, 4) void chamfer_all(
    const float* __restrict__ p1, const float* __restrict__ p2,
    float* __restrict__ out)
{
    __shared__ half8 REC[HOTH];   // 32 KB -> 4 blocks/CU, 4 waves/SIMD
    __shared__ float ws4[4];

    const int tid  = threadIdx.x;
    const int lane = tid & 63;
    const int n    = lane & 31;   // A row (self) / B col (other)
    const int grp  = lane >> 5;   // K-group
    const int wv   = tid >> 6;    // 0..3
    const int blk  = blockIdx.x;
    const int tile = blk & 31;    // fastest: 32 blocks share one other-set (L2)
    const int b    = (blk >> 5) & 15;
    const int dir  = blk >> 9;

    const float* selfp  = (dir ? p2 : p1) + (size_t)b * NPTS * 3;
    const float* otherp = (dir ? p1 : p2) + (size_t)b * NPTS * 3;

    // ---- A fragment: 32 selves per wave ----
    half8 a; float ssq;
    {
        const int s = tile * 128 + wv * 32 + n;
        const float x = selfp[s * 3], y = selfp[s * 3 + 1], z = selfp[s * 3 + 2];
        ssq = fmaf(x, x, fmaf(y, y, z * z));
        _Float16 hx = (_Float16)x, hy = (_Float16)y, hz = (_Float16)z;
        _Float16 lx = (_Float16)(x - (float)hx);
        _Float16 ly = (_Float16)(y - (float)hy);
        _Float16 lz = (_Float16)(z - (float)hz);
        const _Float16 c0 = (_Float16)0.f, c1 = (_Float16)1.f;
        if (grp == 0) { a[0]=hx; a[1]=hy; a[2]=hz; a[3]=c0; a[4]=c0; a[5]=c0; a[6]=c1; a[7]=c0; }
        else          { a[0]=lx; a[1]=ly; a[2]=lz; a[3]=hx; a[4]=hy; a[5]=hz; a[6]=c0; a[7]=c1; }
    }

    f32x16 m, zc;
#pragma unroll
    for (int r = 0; r < 16; ++r) { m[r] = 3.4e38f; zc[r] = 0.f; }

    for (int c = 0; c < NCH; ++c) {
        __syncthreads();   // REC safe to overwrite (all reads of prev chunk done)
        {   // Stage 8 others/thread. REC[k*256+tid]: 16 B lane stride -> no
            // bank conflicts. The k-permutation is min-invariant.
            const float4* src = (const float4*)(otherp + (size_t)c * HOTH * 3);
            float4 v0 = src[tid*6+0], v1 = src[tid*6+1], v2 = src[tid*6+2];
            float4 v3 = src[tid*6+3], v4 = src[tid*6+4], v5 = src[tid*6+5];
            float ox[8] = {v0.x, v0.w, v1.z, v2.y, v3.x, v3.w, v4.z, v5.y};
            float oy[8] = {v0.y, v1.x, v1.w, v2.z, v3.y, v4.x, v4.w, v5.z};
            float oz[8] = {v0.z, v1.y, v2.x, v2.w, v3.z, v4.y, v5.x, v5.w};
#pragma unroll
            for (int k = 0; k < 8; ++k) {
                float gx = -2.f * ox[k], gy = -2.f * oy[k], gz = -2.f * oz[k];
                float q  = fmaf(ox[k], ox[k], fmaf(oy[k], oy[k], oz[k] * oz[k]));
                _Float16 ghx = (_Float16)gx, ghy = (_Float16)gy, ghz = (_Float16)gz;
                half8 r;
                r[0] = ghx; r[1] = ghy; r[2] = ghz;
                r[3] = (_Float16)(gx - (float)ghx);
                r[4] = (_Float16)(gy - (float)ghy);
                r[5] = (_Float16)(gz - (float)ghz);
                _Float16 qh = (_Float16)q;
                r[6] = qh;
                r[7] = (_Float16)(q - (float)qh);
                REC[k * 256 + tid] = r;
            }
        }
        __syncthreads();

        // 32 rounds: 2 ds_read_b128 (upper lanes broadcast) feed 2 MFMAs.
        const half8* rp = REC + n;
#pragma unroll 2
        for (int g = 0; g < 32; ++g) {
            half8 b0 = rp[g * 64];
            half8 b1 = rp[g * 64 + 32];
            f32x16 o0 = __builtin_amdgcn_mfma_f32_32x32x16_f16(a, b0, zc, 0, 0, 0);
            f32x16 o1 = __builtin_amdgcn_mfma_f32_32x32x16_f16(a, b1, zc, 0, 0, 0);
#pragma unroll
            for (int r = 0; r < 16; ++r)
                m[r] = fminf(fminf(o0[r], o1[r]), m[r]);   // v_min3_f32
        }
    }

    // ---- epilogue: min over 32 cols, sum rows, add |s|^2, one atomic ----
#pragma unroll
    for (int mask = 1; mask <= 16; mask <<= 1)
#pragma unroll
        for (int r = 0; r < 16; ++r)
            m[r] = fminf(m[r], __shfl_xor((float)m[r], mask));

    float rowsum = 0.f;
#pragma unroll
    for (int r = 0; r < 16; ++r) rowsum += m[r];
    rowsum += __shfl_xor(rowsum, 32);       // other K-group's 16 rows

    float sv = grp ? 0.f : ssq;             // each self counted once
#pragma unroll
    for (int mask = 1; mask <= 16; mask <<= 1) sv += __shfl_xor(sv, mask);

    if (lane == 0) ws4[wv] = rowsum + sv;
    __syncthreads();
    if (tid == 0)
        atomicAdd(out, (ws4[0] + ws4[1] + ws4[2] + ws4[3]) * (1.0f / BATCH));
}

extern "C" void kernel_launch(void* const* d_in, const int* in_sizes, int n_in,
                              void* d_out, int out_size, void* d_ws, size_t ws_size,
                              hipStream_t stream) {
    const float* p1 = (const float*)d_in[0];
    const float* p2 = (const float*)d_in[1];
    // No workspace usage: out[0] is zeroed by the harness each iteration and
    // accumulated via device-scope float atomics (error << 5.88 threshold).
    chamfer_all<<<dim3(NBLK), dim3(BLOCK), 0, stream>>>(p1, p2, (float*)d_out);
}